// Round 5
// baseline (1151.653 us; speedup 1.0000x reference)
//
#include <hip/hip_runtime.h>
#include <hip/hip_bf16.h>

typedef unsigned short u16;
typedef __attribute__((ext_vector_type(4))) float f32x4;
typedef __attribute__((ext_vector_type(8))) short bf16x8;

#define BZ 64
#define LSEQ 2048
#define DDIM 512
#define UDIM 512
#define ADIM 512
#define VOC 32000
#define EDIM 256

__device__ __forceinline__ u16 f2bf(float f) {
    union { float f; unsigned int u; } v; v.f = f;
    unsigned int u = v.u;
    return (u16)((u + 0x7FFFu + ((u >> 16) & 1u)) >> 16);
}

__device__ __forceinline__ float fast_tanh(float x) {
    x = fminf(fmaxf(x, -15.f), 15.f);
    float e = __expf(2.f * x);
    return (e - 1.f) * __frcp_rn(e + 1.f);
}

// ---------------- zero accumulators (contiguous region) ----------------
__global__ void zero_k(float4* p, int n) {
    int i = blockIdx.x * 256 + threadIdx.x;
    if (i < n) { float4 z; z.x = z.y = z.z = z.w = 0.f; p[i] = z; }
}

// ---------------- multi-job tiled transpose + fp32->bf16 pack ----------------
#define MAXTJ 16
struct TJob { const float* src; u16* dst; int R, C, ld, tileEnd; };
struct TArgs { TJob j[MAXTJ]; int nj; };

__global__ __launch_bounds__(256) void transpose_pack(TArgs a) {
    __shared__ float ts[32][33];
    int bid = blockIdx.x;
    int ji = 0;
    while (bid >= a.j[ji].tileEnd) ji++;
    int tstart = ji ? a.j[ji - 1].tileEnd : 0;
    int local = bid - tstart;
    TJob J = a.j[ji];
    int tilesC = J.C >> 5;
    int tr = local / tilesC, tc = local - tr * tilesC;
    int r0 = tr << 5, c0 = tc << 5;
    int t = threadIdx.x, col = t & 31, row0 = t >> 5;
    #pragma unroll
    for (int i = 0; i < 4; i++) {
        int r = row0 + i * 8;
        ts[r][col] = J.src[(size_t)(r0 + r) * J.C + c0 + col];
    }
    __syncthreads();
    #pragma unroll
    for (int i = 0; i < 4; i++) {
        int crow = row0 + i * 8;
        J.dst[(size_t)(c0 + crow) * J.ld + r0 + col] = f2bf(ts[col][crow]);
    }
}

// ---------------- pack prev_target + prev_hidden to bf16 ----------------
__global__ void pack_misc(const float* __restrict__ pt, const float* __restrict__ ph,
                          u16* __restrict__ ptb, u16* __restrict__ phb) {
    int idx = blockIdx.x * 256 + threadIdx.x;
    if (idx < BZ * VOC) ptb[idx] = f2bf(pt[idx]);
    int i2 = idx - BZ * VOC;
    if (i2 >= 0 && i2 < BZ * UDIM) phb[i2] = f2bf(ph[i2]);
}

// ---------------- prep: featbf[row][0..511]=bf16(feat), [512..575]=bf16(conv) ----------------
__global__ __launch_bounds__(256) void prep_feat_k(
    const float* __restrict__ feat, const float* __restrict__ Bm,
    const float* __restrict__ Qk, u16* __restrict__ featbf)
{
    __shared__ float qs[448];
    __shared__ float bwin[72];
    int t = threadIdx.x;
    int row0 = blockIdx.x * 64;
    int b = row0 >> 11, l0 = row0 & 2047;
    if (t < 448) qs[t] = Qk[t];
    if (t < 70) { int l = l0 - 3 + t; bwin[t] = (l >= 0 && l < LSEQ) ? Bm[b * LSEQ + l] : 0.f; }
    __syncthreads();
    #pragma unroll
    for (int it = 0; it < 8; it++) {
        int r = it * 8 + (t >> 5), c = (t & 31) * 16;
        const float* p = feat + (size_t)(row0 + r) * DDIM + c;
        float4 a0 = *(const float4*)p, a1 = *(const float4*)(p + 4),
               a2 = *(const float4*)(p + 8), a3 = *(const float4*)(p + 12);
        u16 u[16] = { f2bf(a0.x), f2bf(a0.y), f2bf(a0.z), f2bf(a0.w),
                      f2bf(a1.x), f2bf(a1.y), f2bf(a1.z), f2bf(a1.w),
                      f2bf(a2.x), f2bf(a2.y), f2bf(a2.z), f2bf(a2.w),
                      f2bf(a3.x), f2bf(a3.y), f2bf(a3.z), f2bf(a3.w) };
        u16* dst = featbf + (size_t)(row0 + r) * 576 + c;
        *(uint4*)dst = *(uint4*)u;
        *(uint4*)(dst + 8) = *(uint4*)(u + 8);
    }
    {
        int r = t >> 2, c = (t & 3) * 16;
        float s[16];
        #pragma unroll
        for (int j = 0; j < 16; j++) s[j] = 0.f;
        #pragma unroll
        for (int w7 = 0; w7 < 7; w7++) {
            float bv = bwin[r + w7];
            #pragma unroll
            for (int j = 0; j < 16; j++) s[j] += bv * qs[w7 * 64 + c + j];
        }
        u16 u[16];
        #pragma unroll
        for (int j = 0; j < 16; j++) u[j] = f2bf(s[j]);
        u16* dst = featbf + (size_t)(row0 + r) * 576 + 512 + c;
        *(uint4*)dst = *(uint4*)u;
        *(uint4*)(dst + 8) = *(uint4*)(u + 8);
    }
}

// ---------------- batched small GEMM: 64(M) x 64(N) tiles, split-K atomics ----------------
#define MAXGJ 4
struct GJob { const u16* A; const u16* Bt; float* C;
              int ldA, ldB, ldC, nT, ckPer, ckTot, tileEnd, store; };
struct GArgs { GJob j[MAXGJ]; };

__global__ __launch_bounds__(256) void gemm_batch_k(GArgs ga) {
    __shared__ u16 As[64 * 40];
    __shared__ u16 Bs[64 * 40];
    int bid = blockIdx.x, ji = 0;
    while (bid >= ga.j[ji].tileEnd) ji++;
    GJob J = ga.j[ji];
    int local = bid - (ji ? ga.j[ji - 1].tileEnd : 0);
    int nti = local % J.nT, ksi = local / J.nT;
    int n0 = nti * 64;
    int ck0 = ksi * J.ckPer;
    int ckEnd = ck0 + J.ckPer; if (ckEnd > J.ckTot) ckEnd = J.ckTot;
    int tid = threadIdx.x, w = tid >> 6, lane = tid & 63, q = lane >> 4, cc = lane & 15;
    int wrow = lane >> 2, wseg = lane & 3;
    int m = w * 16 + wrow;
    f32x4 acc[4];
    #pragma unroll
    for (int mt = 0; mt < 4; mt++) acc[mt] = (f32x4)0.f;
    const u16* Ab = J.A + (size_t)m * J.ldA + wseg * 8;
    const u16* Bb = J.Bt + (size_t)(n0 + m) * J.ldB + wseg * 8;
    for (int ck = ck0; ck < ckEnd; ck++) {
        int k0 = ck * 32;
        *(uint4*)&As[m * 40 + wseg * 8] = *(const uint4*)(Ab + k0);
        *(uint4*)&Bs[m * 40 + wseg * 8] = *(const uint4*)(Bb + k0);
        __syncthreads();
        bf16x8 af[4];
        #pragma unroll
        for (int mt = 0; mt < 4; mt++)
            af[mt] = *(const bf16x8*)&As[(mt * 16 + cc) * 40 + q * 8];
        bf16x8 bfr = *(const bf16x8*)&Bs[(w * 16 + cc) * 40 + q * 8];
        #pragma unroll
        for (int mt = 0; mt < 4; mt++)
            acc[mt] = __builtin_amdgcn_mfma_f32_16x16x32_bf16(af[mt], bfr, acc[mt], 0, 0, 0);
        __syncthreads();
    }
    #pragma unroll
    for (int mt = 0; mt < 4; mt++) {
        #pragma unroll
        for (int rr = 0; rr < 4; rr++) {
            int mm = mt * 16 + q * 4 + rr, n = n0 + w * 16 + cc;
            float v = acc[mt][rr];
            if (J.store) J.C[(size_t)mm * J.ldC + n] = v;
            else atomicAdd(&J.C[(size_t)mm * J.ldC + n], v);
        }
    }
}

// ---------------- attention GEMM: 128x128 tile, BK=64, VGPR prefetch dbuf ----------------
__global__ __launch_bounds__(256) void attn_gemm_k(
    const u16* __restrict__ featbf, const u16* __restrict__ Wt,
    const float* __restrict__ hWa, const float* __restrict__ Va,
    float* __restrict__ e)
{
    __shared__ u16 As[128 * 72];
    __shared__ u16 Bs[128 * 72];
    // XCD swizzle: 4 col-tiles of one row-tile adjacent on one XCD (validated R4: FETCH 298->76MB)
    int bid = blockIdx.x;
    int job = (bid & 7) * 512 + (bid >> 3);
    int row0 = (job >> 2) * 128;
    int col0 = (job & 3) * 128;
    int b = row0 >> 11;
    int tid = threadIdx.x, w = tid >> 6, lane = tid & 63, q = lane >> 4, cc = lane & 15;
    int rh = w & 1, ch = w >> 1;
    // staging map: 256 thr x 16B; thread covers rows srow+p*32 (p=0..3), col seg sseg*8 of 64
    int srow = tid >> 3, sseg = tid & 7;
    const u16* Ag = featbf + (size_t)(row0 + srow) * 576 + sseg * 8;
    const u16* Bg = Wt + (size_t)(col0 + srow) * 576 + sseg * 8;
    uint4 pa[4], pb[4];
    #pragma unroll
    for (int p = 0; p < 4; p++) {
        pa[p] = *(const uint4*)(Ag + (size_t)p * 32 * 576);
        pb[p] = *(const uint4*)(Bg + (size_t)p * 32 * 576);
    }
    f32x4 acc[4][4];
    #pragma unroll
    for (int mt = 0; mt < 4; mt++)
        #pragma unroll
        for (int nt = 0; nt < 4; nt++) acc[mt][nt] = (f32x4)0.f;

    for (int ck = 0; ck < 9; ck++) {
        if (ck) __syncthreads();                 // prev-chunk consumers done
        #pragma unroll
        for (int p = 0; p < 4; p++) {
            *(uint4*)&As[(srow + p * 32) * 72 + sseg * 8] = pa[p];
            *(uint4*)&Bs[(srow + p * 32) * 72 + sseg * 8] = pb[p];
        }
        __syncthreads();
        if (ck < 8) {                            // prefetch next chunk under compute
            int k0 = (ck + 1) * 64;
            #pragma unroll
            for (int p = 0; p < 4; p++) {
                pa[p] = *(const uint4*)(Ag + (size_t)p * 32 * 576 + k0);
                pb[p] = *(const uint4*)(Bg + (size_t)p * 32 * 576 + k0);
            }
        }
        #pragma unroll
        for (int kk = 0; kk < 2; kk++) {
            bf16x8 af[4], bfr[4];
            #pragma unroll
            for (int mt = 0; mt < 4; mt++)
                af[mt] = *(const bf16x8*)&As[(rh * 64 + mt * 16 + cc) * 72 + kk * 32 + q * 8];
            #pragma unroll
            for (int nt = 0; nt < 4; nt++)
                bfr[nt] = *(const bf16x8*)&Bs[(ch * 64 + nt * 16 + cc) * 72 + kk * 32 + q * 8];
            #pragma unroll
            for (int mt = 0; mt < 4; mt++)
                #pragma unroll
                for (int nt = 0; nt < 4; nt++)
                    acc[mt][nt] = __builtin_amdgcn_mfma_f32_16x16x32_bf16(af[mt], bfr[nt], acc[mt][nt], 0, 0, 0);
        }
    }
    float hv[4], vv[4];
    #pragma unroll
    for (int nt = 0; nt < 4; nt++) {
        int n = col0 + ch * 64 + nt * 16 + cc;
        hv[nt] = hWa[b * ADIM + n];
        vv[nt] = Va[n];
    }
    #pragma unroll
    for (int mt = 0; mt < 4; mt++) {
        #pragma unroll
        for (int rr = 0; rr < 4; rr++) {
            float s = 0.f;
            #pragma unroll
            for (int nt = 0; nt < 4; nt++)
                s += fast_tanh(hv[nt] + acc[mt][nt][rr]) * vv[nt];
            s += __shfl_xor(s, 1, 16);
            s += __shfl_xor(s, 2, 16);
            s += __shfl_xor(s, 4, 16);
            s += __shfl_xor(s, 8, 16);
            if (cc == 0)
                atomicAdd(&e[row0 + rh * 64 + mt * 16 + q * 4 + rr], s);
        }
    }
}

// ---------------- softmax over L per batch ----------------
__global__ __launch_bounds__(256) void softmaxL_k(const float* __restrict__ e,
                                                  float* __restrict__ attn_ws,
                                                  float* __restrict__ attn_out) {
    int b = blockIdx.x, t = threadIdx.x;
    __shared__ float sm[4], ss[4];
    float v[8];
    float mx = -1e30f;
    #pragma unroll
    for (int i = 0; i < 8; i++) { v[i] = e[b * LSEQ + t + i * 256]; mx = fmaxf(mx, v[i]); }
    for (int o = 32; o; o >>= 1) mx = fmaxf(mx, __shfl_xor(mx, o, 64));
    if ((t & 63) == 0) sm[t >> 6] = mx;
    __syncthreads();
    mx = fmaxf(fmaxf(sm[0], sm[1]), fmaxf(sm[2], sm[3]));
    float s = 0.f;
    #pragma unroll
    for (int i = 0; i < 8; i++) { v[i] = __expf(v[i] - mx); s += v[i]; }
    for (int o = 32; o; o >>= 1) s += __shfl_xor(s, o, 64);
    if ((t & 63) == 0) ss[t >> 6] = s;
    __syncthreads();
    s = ss[0] + ss[1] + ss[2] + ss[3];
    float inv = 1.f / s;
    #pragma unroll
    for (int i = 0; i < 8; i++) {
        float p = v[i] * inv;
        attn_ws[b * LSEQ + t + i * 256] = p;
        attn_out[b * LSEQ + t + i * 256] = p;
    }
}

// ---------------- context = sum_l attn * feat (bf16 source), L-split atomics ----------------
__global__ __launch_bounds__(256) void context2_k(
    const u16* __restrict__ featbf, const float* __restrict__ attn,
    float* __restrict__ ctx)
{
    __shared__ float at[256];
    int t = threadIdx.x, b = blockIdx.y, lc = blockIdx.x;
    at[t] = attn[b * LSEQ + lc * 256 + t];
    __syncthreads();
    int col = t * 2;
    const u16* base = featbf + (size_t)(b * LSEQ + lc * 256) * 576 + col;
    float a0 = 0.f, a1 = 0.f;
    #pragma unroll 4
    for (int l = 0; l < 256; l++) {
        unsigned int u = *(const unsigned int*)(base + (size_t)l * 576);
        union { unsigned int i; float f; } lo, hi;
        lo.i = u << 16; hi.i = u & 0xffff0000u;
        float av = at[l];
        a0 += av * lo.f;
        a1 += av * hi.f;
    }
    atomicAdd(&ctx[b * UDIM + col], a0);
    atomicAdd(&ctx[b * UDIM + col + 1], a1);
}

// ---------------- pack / elementwise kernels ----------------
__global__ void pack_acat1_k(const float* __restrict__ Ey, const float* __restrict__ h,
                             const float* __restrict__ ctx, u16* __restrict__ Acat1,
                             const float* __restrict__ bwyh, const float* __restrict__ burh,
                             float* __restrict__ bsum) {
    int b = blockIdx.x, t = threadIdx.x;
    for (int col = t; col < 1280; col += 256) {
        float v = (col < 256) ? Ey[b * 256 + col]
                : (col < 768) ? h[b * 512 + col - 256]
                              : ctx[b * 512 + col - 768];
        Acat1[b * 1280 + col] = f2bf(v);
    }
    if (b == 0) { for (int i = t; i < 512; i += 256) bsum[i] = bwyh[i] + burh[i]; }
}

__global__ void pack_acath_k(const float* __restrict__ Ey, const float* __restrict__ rtp,
                             const float* __restrict__ h, u16* __restrict__ AcatH) {
    int b = blockIdx.x, t = threadIdx.x;
    for (int col = t; col < 768; col += 256) {
        float v;
        if (col < 256) v = Ey[b * 256 + col];
        else {
            int u = col - 256;
            float rt = 1.f / (1.f + __expf(-rtp[b * 512 + u]));
            v = rt * h[b * 512 + u];
        }
        AcatH[b * 768 + col] = f2bf(v);
    }
}

__global__ void pack_ht3_k(const float* __restrict__ ztp, const float* __restrict__ hcp,
                           const float* __restrict__ ccz, const float* __restrict__ bsum,
                           const float* __restrict__ h, const float* __restrict__ ctx,
                           float* __restrict__ ht_out, u16* __restrict__ Acat3) {
    int b = blockIdx.x, t = threadIdx.x;
    for (int u = t; u < 512; u += 256) {
        float z = 1.f / (1.f + __expf(-ztp[b * 512 + u]));
        float hcv = tanhf(hcp[b * 512 + u] + ccz[b * 512 + u] + bsum[u]);
        float v = (1.f - z) * h[b * 512 + u] + z * hcv;
        ht_out[b * 512 + u] = v;
        Acat3[b * 1024 + u] = f2bf(v);
        Acat3[b * 1024 + 512 + u] = f2bf(ctx[b * 512 + u]);
    }
}

__global__ void pack_G_k(const float* __restrict__ Gf32, const float* __restrict__ Ey,
                         u16* __restrict__ Gbf) {
    int b = blockIdx.x, t = threadIdx.x;
    Gbf[b * 256 + t] = f2bf(Gf32[b * 256 + t] + Ey[b * 256 + t]);
}

// ---------------- softmax over V ----------------
__global__ __launch_bounds__(1024) void softmaxV_k(const float* __restrict__ logits,
                                                   float* __restrict__ out) {
    int b = blockIdx.x, t = threadIdx.x;
    __shared__ float sm[16], ss[16];
    const float* lp = logits + (size_t)b * VOC;
    float mx = -1e30f;
    for (int i = t; i < VOC; i += 1024) mx = fmaxf(mx, lp[i]);
    for (int o = 32; o; o >>= 1) mx = fmaxf(mx, __shfl_xor(mx, o, 64));
    if ((t & 63) == 0) sm[t >> 6] = mx;
    __syncthreads();
    if (t < 16) {
        float m2 = sm[t];
        for (int o = 8; o; o >>= 1) m2 = fmaxf(m2, __shfl_xor(m2, o, 16));
        sm[t] = m2;
    }
    __syncthreads();
    mx = sm[0];
    float s = 0.f;
    for (int i = t; i < VOC; i += 1024) s += __expf(lp[i] - mx);
    for (int o = 32; o; o >>= 1) s += __shfl_xor(s, o, 64);
    if ((t & 63) == 0) ss[t >> 6] = s;
    __syncthreads();
    if (t < 16) {
        float s2 = ss[t];
        for (int o = 8; o; o >>= 1) s2 += __shfl_xor(s2, o, 16);
        ss[t] = s2;
    }
    __syncthreads();
    float inv = 1.f / ss[0];
    float* op = out + (size_t)b * VOC;
    for (int i = t; i < VOC; i += 1024) op[i] = __expf(lp[i] - mx) * inv;
}

// ---------------- workspace layout (bytes) ----------------
#define OFF_FEATBF ((size_t)0)           // 150,994,944 (dead after context2_k; logits aliases)
#define OFF_WTCAT  ((size_t)150994944)
#define OFF_WTWA   ((size_t)151584768)
#define OFF_WTWE   ((size_t)152109056)
#define OFF_WTWO   ((size_t)168493056)
#define OFF_WTHC   ((size_t)184877056)
#define OFF_WTZ    ((size_t)185401344)
#define OFF_WTR    ((size_t)186712064)
#define OFF_WTH    ((size_t)188022784)
#define OFF_PTB    ((size_t)188809216)
#define OFF_PHB    ((size_t)192905216)
// zeroed region start
#define OFF_E      ((size_t)192970752)   // 524288
#define OFF_HWA    ((size_t)193495040)   // 131072
#define OFF_EY     ((size_t)193626112)   // 65536
#define OFF_CTX    ((size_t)193691648)   // 131072
#define OFF_ZTP    ((size_t)193822720)   // 131072
#define OFF_RTP    ((size_t)193953792)   // 131072
#define OFF_CCZ    ((size_t)194084864)   // 131072
#define OFF_HCP    ((size_t)194215936)   // 131072
#define OFF_GF32   ((size_t)194347008)   // 65536
// zeroed region end: 194412544 (1,441,792 B = 90112 float4)
#define OFF_ATTNWS ((size_t)194412544)   // 524288
#define OFF_ACAT1  ((size_t)194936832)   // 163840
#define OFF_ACATH  ((size_t)195100672)   // 98304
#define OFF_ACAT3  ((size_t)195198976)   // 131072
#define OFF_BSUM   ((size_t)195330048)   // 2048
#define OFF_GBF    ((size_t)195332096)   // 32768
#define OFF_LOGITS OFF_FEATBF

extern "C" void kernel_launch(void* const* d_in, const int* in_sizes, int n_in,
                              void* d_out, int out_size, void* d_ws, size_t ws_size,
                              hipStream_t stream)
{
    const float* prev_target = (const float*)d_in[0];
    const float* prev_hidden = (const float*)d_in[1];
    const float* features    = (const float*)d_in[2];
    const float* Bmat        = (const float*)d_in[3];
    const float* Wa    = (const float*)d_in[4];
    const float* Ua    = (const float*)d_in[5];
    const float* Va    = (const float*)d_in[6];
    const float* Uf    = (const float*)d_in[7];
    const float* Qk    = (const float*)d_in[8];
    const float* We    = (const float*)d_in[9];
    const float* Wccz  = (const float*)d_in[10];
    const float* Wyz   = (const float*)d_in[11];
    const float* Uhz   = (const float*)d_in[12];
    const float* Wyr   = (const float*)d_in[13];
    const float* Uhr   = (const float*)d_in[14];
    const float* Ccr   = (const float*)d_in[15];
    const float* Wyh   = (const float*)d_in[16];
    const float* b_wyh = (const float*)d_in[17];
    const float* Urh   = (const float*)d_in[18];
    const float* b_urh = (const float*)d_in[19];
    const float* Wo    = (const float*)d_in[20];
    const float* Wh    = (const float*)d_in[21];
    const float* Wc    = (const float*)d_in[22];

    char* w = (char*)d_ws;
    u16*   featbf  = (u16*)(w + OFF_FEATBF);
    u16*   Wt_cat  = (u16*)(w + OFF_WTCAT);
    u16*   Wt_wa   = (u16*)(w + OFF_WTWA);
    u16*   Wt_we   = (u16*)(w + OFF_WTWE);
    u16*   Wt_wo   = (u16*)(w + OFF_WTWO);
    u16*   Wt_hc   = (u16*)(w + OFF_WTHC);
    u16*   Wt_z    = (u16*)(w + OFF_WTZ);
    u16*   Wt_r    = (u16*)(w + OFF_WTR);
    u16*   Wt_h    = (u16*)(w + OFF_WTH);
    u16*   pt_bf   = (u16*)(w + OFF_PTB);
    u16*   ph_bf   = (u16*)(w + OFF_PHB);
    float* e_buf   = (float*)(w + OFF_E);
    float* hWa_buf = (float*)(w + OFF_HWA);
    float* Ey_buf  = (float*)(w + OFF_EY);
    float* ctx_buf = (float*)(w + OFF_CTX);
    float* ztp_buf = (float*)(w + OFF_ZTP);
    float* rtp_buf = (float*)(w + OFF_RTP);
    float* ccz_buf = (float*)(w + OFF_CCZ);
    float* hcp_buf = (float*)(w + OFF_HCP);
    float* Gf32    = (float*)(w + OFF_GF32);
    float* attn_ws = (float*)(w + OFF_ATTNWS);
    u16*   Acat1   = (u16*)(w + OFF_ACAT1);
    u16*   AcatH   = (u16*)(w + OFF_ACATH);
    u16*   Acat3   = (u16*)(w + OFF_ACAT3);
    float* bsum    = (float*)(w + OFF_BSUM);
    u16*   Gbf     = (u16*)(w + OFF_GBF);
    float* logits  = (float*)(w + OFF_LOGITS);

    float* out      = (float*)d_out;
    float* ht_out   = out + (size_t)BZ * VOC;
    float* attn_out = ht_out + (size_t)BZ * UDIM;

    // ---- transpose jobs (Bt[n][k] = W[k][n]) ----
    TArgs ta;
    int cum = 0, ji = 0;
    auto addJob = [&](const float* src, u16* dst, int R, int C, int ld) {
        cum += (R / 32) * (C / 32);
        ta.j[ji].src = src; ta.j[ji].dst = dst;
        ta.j[ji].R = R; ta.j[ji].C = C; ta.j[ji].ld = ld; ta.j[ji].tileEnd = cum;
        ji++;
    };
    addJob(Ua,   Wt_cat + 0,   512, 512, 576);
    addJob(Uf,   Wt_cat + 512,  64, 512, 576);
    addJob(Wa,   Wt_wa,        512, 512, 512);
    addJob(We,   Wt_we,      32000, 256, 32000);
    addJob(Wo,   Wt_wo,        256, 32000, 256);
    addJob(Wh,   Wt_hc + 0,    512, 256, 1024);
    addJob(Wc,   Wt_hc + 512,  512, 256, 1024);
    addJob(Wyz,  Wt_z + 0,     256, 512, 1280);
    addJob(Uhz,  Wt_z + 256,   512, 512, 1280);
    addJob(Wccz, Wt_z + 768,   512, 512, 1280);
    addJob(Wyr,  Wt_r + 0,     256, 512, 1280);
    addJob(Uhr,  Wt_r + 256,   512, 512, 1280);
    addJob(Ccr,  Wt_r + 768,   512, 512, 1280);
    addJob(Wyh,  Wt_h + 0,     256, 512, 768);
    addJob(Urh,  Wt_h + 256,   512, 512, 768);
    ta.nj = ji;

    // ---- small-GEMM job builder ----
    auto mkjob = [](const u16* A, int ldA, const u16* Bt, int ldB, float* C, int ldC,
                    int N, int K, int ckPer, int& c2) {
        GJob g; g.A = A; g.Bt = Bt; g.C = C; g.ldA = ldA; g.ldB = ldB; g.ldC = ldC;
        g.nT = N / 64; g.ckTot = K / 32; g.ckPer = ckPer;
        int ks = (g.ckTot + ckPer - 1) / ckPer;
        c2 += g.nT * ks; g.tileEnd = c2;
        g.store = (ckPer >= g.ckTot) ? 1 : 0;
        return g;
    };

    // 1. zero accumulators (e..Gf32)
    hipLaunchKernelGGL(zero_k, dim3(352), dim3(256), 0, stream, (float4*)e_buf, 90112);
    // 2. weight transposes
    hipLaunchKernelGGL(transpose_pack, dim3(cum), dim3(256), 0, stream, ta);
    // 3. pack prev_target / prev_hidden
    hipLaunchKernelGGL(pack_misc, dim3(8128), dim3(256), 0, stream,
                       prev_target, prev_hidden, pt_bf, ph_bf);
    // 4. features -> bf16 + fused conv
    hipLaunchKernelGGL(prep_feat_k, dim3(2048), dim3(256), 0, stream,
                       features, Bmat, Qk, featbf);
    // 5. batch A: hWa (K=512, split 4) + Ey (K=32000, split 100)
    {
        GArgs ga; int c2 = 0;
        ga.j[0] = mkjob(ph_bf, 512, Wt_wa, 512, hWa_buf, 512, 512, 512, 4, c2);
        ga.j[1] = mkjob(pt_bf, 32000, Wt_we, 32000, Ey_buf, 256, 256, 32000, 10, c2);
        hipLaunchKernelGGL(gemm_batch_k, dim3(c2), dim3(256), 0, stream, ga);
    }
    // 6. attention scores
    hipLaunchKernelGGL(attn_gemm_k, dim3(4096), dim3(256), 0, stream,
                       featbf, Wt_cat, hWa_buf, Va, e_buf);
    // 7. softmax over L
    hipLaunchKernelGGL(softmaxL_k, dim3(64), dim3(256), 0, stream, e_buf, attn_ws, attn_out);
    // 8. context
    hipLaunchKernelGGL(context2_k, dim3(8, 64), dim3(256), 0, stream,
                       featbf, attn_ws, ctx_buf);
    // 9. Acat1 + bsum
    hipLaunchKernelGGL(pack_acat1_k, dim3(64), dim3(256), 0, stream,
                       Ey_buf, prev_hidden, ctx_buf, Acat1, b_wyh, b_urh, bsum);
    // 10. batch B: ztp, rtp (K=1280, split 8x), ccz (K=512, split 4x)
    {
        GArgs ga; int c2 = 0;
        ga.j[0] = mkjob(Acat1, 1280, Wt_z, 1280, ztp_buf, 512, 512, 1280, 5, c2);
        ga.j[1] = mkjob(Acat1, 1280, Wt_r, 1280, rtp_buf, 512, 512, 1280, 5, c2);
        ga.j[2] = mkjob(Acat1 + 768, 1280, Wt_z + 768, 1280, ccz_buf, 512, 512, 512, 4, c2);
        hipLaunchKernelGGL(gemm_batch_k, dim3(c2), dim3(256), 0, stream, ga);
    }
    // 11. AcatH = [Ey | sigmoid(rtp)*h]
    hipLaunchKernelGGL(pack_acath_k, dim3(64), dim3(256), 0, stream,
                       Ey_buf, rtp_buf, prev_hidden, AcatH);
    // 12. batch C: hcp (K=768, split 8x)
    {
        GArgs ga; int c2 = 0;
        ga.j[0] = mkjob(AcatH, 768, Wt_h, 768, hcp_buf, 512, 512, 768, 3, c2);
        hipLaunchKernelGGL(gemm_batch_k, dim3(c2), dim3(256), 0, stream, ga);
    }
    // 13. ht + Acat3
    hipLaunchKernelGGL(pack_ht3_k, dim3(64), dim3(256), 0, stream,
                       ztp_buf, hcp_buf, ccz_buf, bsum, prev_hidden, ctx_buf, ht_out, Acat3);
    // 14. batch D: Gf32 = [ht|ctx]@[Wh;Wc] (K=1024, split 8x)
    {
        GArgs ga; int c2 = 0;
        ga.j[0] = mkjob(Acat3, 1024, Wt_hc, 1024, Gf32, 256, 256, 1024, 4, c2);
        hipLaunchKernelGGL(gemm_batch_k, dim3(c2), dim3(256), 0, stream, ga);
    }
    // 15. Gbf = bf16(Gf32 + Ey)
    hipLaunchKernelGGL(pack_G_k, dim3(64), dim3(256), 0, stream, Gf32, Ey_buf, Gbf);
    // 16. batch E: logits = Gbf @ Wo (K=256, store)
    {
        GArgs ga; int c2 = 0;
        ga.j[0] = mkjob(Gbf, 256, Wt_wo, 256, logits, 32000, 32000, 256, 8, c2);
        hipLaunchKernelGGL(gemm_batch_k, dim3(c2), dim3(256), 0, stream, ga);
    }
    // 17. softmax over V
    hipLaunchKernelGGL(softmaxV_k, dim3(64), dim3(1024), 0, stream, logits, out);
}